// Round 4
// baseline (215.170 us; speedup 1.0000x reference)
//
#include <hip/hip_runtime.h>

// DAS beamforming: out[b,z,x,k] = sum_c lerp(rf[b,c], delay(b,c,z,x))[k]
// Round 4: ws is POISON (256 MiB 0xAA re-fill every replay) — never read from
// it. Back to staging rf fp32 directly (clean input lines -> L2 hits, round-1
// measured FETCH=11MB). Keep round 3's 2-blocks/CU occupancy win:
//   512 blocks = 2 batch x 32 tiles x 8 chunks, 1024 thr, LDS 2x32KiB dbuf.
// Epilogue: atomicAdd into out (16.8 MB total, cheaper than partials+reduce),
// out zeroed by memsetAsync. d_ws completely untouched.

#define NBATCH 2
#define NC 128
#define NS 2048
#define NK 4
#define NM 65536                              // Nz*Nx pixels per batch

#define THREADS 1024
#define PX_PER_THREAD 2
#define PX_PER_BLOCK (THREADS * PX_PER_THREAD)   // 2048
#define C_PER_BLOCK 16
#define N_CHUNKS (NC / C_PER_BLOCK)           // 8
#define N_TILES (NM / PX_PER_BLOCK)           // 32
#define NBLOCKS (NBATCH * N_TILES * N_CHUNKS) // 512 = 2 blocks/CU, 32 waves/CU
#define SLICE_F4 (NS * NK / 4)                // 2048 float4 = 32 KiB / channel

// Stage one channel slice (32 KiB) global->LDS async: 2 x 16 B per thread,
// lane-sequential LDS dest as the HW requires.
__device__ __forceinline__ void stage_channel(const float* slice, float4* lbuf, int t) {
#pragma unroll
    for (int r = 0; r < SLICE_F4 / THREADS; ++r) {
        const int d = r * THREADS + t;
        __builtin_amdgcn_global_load_lds(
            (const __attribute__((address_space(1))) void*)(slice + (size_t)d * 4),
            (__attribute__((address_space(3))) void*)(lbuf + d),
            16, 0, 0);
    }
}

__global__ __launch_bounds__(THREADS, 8) void das_kernel(
    const float* __restrict__ rf, const float* __restrict__ g,
    const float* __restrict__ pr, const float* __restrict__ p,
    float* __restrict__ out)
{
    __shared__ float4 sbuf[2][SLICE_F4];   // 2 x 32 KiB double buffer

    const int bid   = blockIdx.x;
    const int chunk = bid & (N_CHUNKS - 1);
    const int tile  = (bid >> 3) & (N_TILES - 1);
    const int b     = bid >> 8;
    const int t     = threadIdx.x;
    const int px0   = tile * PX_PER_BLOCK;

    const float c0v = p[b * 4 + 0];
    const float fsv = p[b * 4 + 1];
    const float t0v = p[b * 4 + 2];
    const float scale = fsv / c0v;            // samples per meter
    const float sb0   = scale * t0v;

    float gx[PX_PER_THREAD], gy[PX_PER_THREAD], gzv[PX_PER_THREAD], sbase[PX_PER_THREAD];
#pragma unroll
    for (int j = 0; j < PX_PER_THREAD; ++j) {
        const int m = px0 + j * THREADS + t;
        const float* gp = g + ((size_t)b * NM + m) * 3;
        gx[j]  = gp[0];
        gy[j]  = gp[1];
        gzv[j] = gp[2];
        sbase[j] = sb0 + scale * gzv[j];      // fs*(t0 + d_tx)/c0 hoisted
    }

    float4 acc[PX_PER_THREAD];
#pragma unroll
    for (int j = 0; j < PX_PER_THREAD; ++j) acc[j] = make_float4(0.f, 0.f, 0.f, 0.f);

    const int ch0 = chunk * C_PER_BLOCK;
    const float* slice0 = rf + (size_t)(b * NC + ch0) * NS * NK;

    stage_channel(slice0, &sbuf[0][0], t);

    for (int cc = 0; cc < C_PER_BLOCK; ++cc) {
        // vmcnt(0)+barrier: drains the stage into sbuf[cc&1] and protects
        // sbuf[(cc+1)&1] from overwrite while still being read. With 2
        // resident blocks/CU the other block computes through this stall.
        __syncthreads();
        if (cc + 1 < C_PER_BLOCK)
            stage_channel(slice0 + (size_t)(cc + 1) * NS * NK,
                          &sbuf[(cc + 1) & 1][0], t);  // in flight during compute

        const float4* lb = &sbuf[cc & 1][0];
        const float* prp = pr + ((size_t)(b * NC + ch0 + cc)) * 3;
        const float prx = prp[0], pry = prp[1], prz = prp[2];

#pragma unroll
        for (int j = 0; j < PX_PER_THREAD; ++j) {
            const float dx = gx[j]  - prx;
            const float dy = gy[j]  - pry;
            const float dz = gzv[j] - prz;
            const float drx = __builtin_amdgcn_sqrtf(fmaf(dx, dx, fmaf(dy, dy, dz * dz)));
            float s = fmaf(scale, drx, sbase[j]);         // fractional sample index
            s = fminf(fmaxf(s, 0.0f), (float)(NS - 1));   // clamp
            const float fi = fminf(floorf(s), (float)(NS - 2));
            const float w  = s - fi;
            const float wm = 1.0f - w;
            const int i0 = (int)fi;
            const float4 y0 = lb[i0];                     // adjacent 32 B:
            const float4 y1 = lb[i0 + 1];                 // 2x ds_read_b128
            acc[j].x = fmaf(y0.x, wm, fmaf(y1.x, w, acc[j].x));
            acc[j].y = fmaf(y0.y, wm, fmaf(y1.y, w, acc[j].y));
            acc[j].z = fmaf(y0.z, wm, fmaf(y1.z, w, acc[j].z));
            acc[j].w = fmaf(y0.w, wm, fmaf(y1.w, w, acc[j].w));
        }
    }

    // 8 chunk-blocks contend per cell; 16.8 MB total atomic traffic.
    float* ob = out + (size_t)b * NM * NK;
#pragma unroll
    for (int j = 0; j < PX_PER_THREAD; ++j) {
        const int m = px0 + j * THREADS + t;
        float* op = ob + (size_t)m * NK;
        atomicAdd(op + 0, acc[j].x);
        atomicAdd(op + 1, acc[j].y);
        atomicAdd(op + 2, acc[j].z);
        atomicAdd(op + 3, acc[j].w);
    }
}

extern "C" void kernel_launch(void* const* d_in, const int* in_sizes, int n_in,
                              void* d_out, int out_size, void* d_ws, size_t ws_size,
                              hipStream_t stream) {
    (void)in_sizes; (void)n_in; (void)d_ws; (void)ws_size;
    const float* rf = (const float*)d_in[0];
    const float* g  = (const float*)d_in[1];
    const float* pr = (const float*)d_in[2];
    const float* p  = (const float*)d_in[3];
    float* out = (float*)d_out;

    // out is poisoned 0xAA before every launch; atomics need zeros.
    hipMemsetAsync(d_out, 0, (size_t)out_size * sizeof(float), stream);
    das_kernel<<<NBLOCKS, THREADS, 0, stream>>>(rf, g, pr, p, out);
}

// Round 5
// 87.047 us; speedup vs baseline: 2.4719x; 2.4719x over previous
//
#include <hip/hip_runtime.h>

// DAS beamforming: out[b,z,x,k] = sum_c lerp(rf[b,c], delay(b,c,z,x))[k]
// Round 5 synthesis of rounds 1-4:
//  - R2's epilogue: per-chunk partials as plain float4 stores into d_ws +
//    reduce kernel. (R4 showed contended atomics are catastrophic: chunk id
//    == blockIdx%8 == XCD id -> 8-way cross-XCD line ping-pong, WRITE_SIZE
//    276 MB, das 165 us. Writes to ws are fine; only READING pre-poisoned ws
//    data is cold (R3 lesson).)
//  - R4's geometry: 512 blocks = 2 batch x 32 tiles x 8 chunks, 1024 thr,
//    2 blocks/CU (128 KiB LDS) so one block computes through the other
//    block's stage-drain barrier.
//  - rf staged fp32 directly from the clean input buffer (L2-resident).

#define NBATCH 2
#define NC 128
#define NS 2048
#define NK 4
#define NM 65536                              // Nz*Nx pixels per batch

#define THREADS 1024
#define PX_PER_THREAD 2
#define PX_PER_BLOCK (THREADS * PX_PER_THREAD)   // 2048
#define C_PER_BLOCK 16
#define N_CHUNKS (NC / C_PER_BLOCK)           // 8
#define N_TILES (NM / PX_PER_BLOCK)           // 32
#define NBLOCKS (NBATCH * N_TILES * N_CHUNKS) // 512 = 2 blocks/CU, 32 waves/CU
#define SLICE_F4 (NS * NK / 4)                // 2048 float4 = 32 KiB / channel

#define PART_BYTES ((size_t)N_CHUNKS * NBATCH * NM * NK * 4)  // 16.8 MB

// Stage one channel slice (32 KiB) global->LDS async: 2 x 16 B per thread,
// lane-sequential LDS dest as the HW requires.
__device__ __forceinline__ void stage_channel(const float* slice, float4* lbuf, int t) {
#pragma unroll
    for (int r = 0; r < SLICE_F4 / THREADS; ++r) {
        const int d = r * THREADS + t;
        __builtin_amdgcn_global_load_lds(
            (const __attribute__((address_space(1))) void*)(slice + (size_t)d * 4),
            (__attribute__((address_space(3))) void*)(lbuf + d),
            16, 0, 0);
    }
}

template <bool ATOMIC>
__global__ __launch_bounds__(THREADS, 8) void das_kernel(
    const float* __restrict__ rf, const float* __restrict__ g,
    const float* __restrict__ pr, const float* __restrict__ p,
    float* __restrict__ dst)    // ATOMIC ? out : partials in ws
{
    __shared__ float4 sbuf[2][SLICE_F4];   // 2 x 32 KiB double buffer

    const int bid   = blockIdx.x;
    const int chunk = bid & (N_CHUNKS - 1);
    const int tile  = (bid >> 3) & (N_TILES - 1);
    const int b     = bid >> 8;
    const int t     = threadIdx.x;
    const int px0   = tile * PX_PER_BLOCK;

    const float c0v = p[b * 4 + 0];
    const float fsv = p[b * 4 + 1];
    const float t0v = p[b * 4 + 2];
    const float scale = fsv / c0v;            // samples per meter
    const float sb0   = scale * t0v;

    float gx[PX_PER_THREAD], gy[PX_PER_THREAD], gzv[PX_PER_THREAD], sbase[PX_PER_THREAD];
#pragma unroll
    for (int j = 0; j < PX_PER_THREAD; ++j) {
        const int m = px0 + j * THREADS + t;
        const float* gp = g + ((size_t)b * NM + m) * 3;
        gx[j]  = gp[0];
        gy[j]  = gp[1];
        gzv[j] = gp[2];
        sbase[j] = sb0 + scale * gzv[j];      // fs*(t0 + d_tx)/c0 hoisted
    }

    float4 acc[PX_PER_THREAD];
#pragma unroll
    for (int j = 0; j < PX_PER_THREAD; ++j) acc[j] = make_float4(0.f, 0.f, 0.f, 0.f);

    const int ch0 = chunk * C_PER_BLOCK;
    const float* slice0 = rf + (size_t)(b * NC + ch0) * NS * NK;

    stage_channel(slice0, &sbuf[0][0], t);

    for (int cc = 0; cc < C_PER_BLOCK; ++cc) {
        // vmcnt(0)+barrier: drains the stage into sbuf[cc&1] and protects
        // sbuf[(cc+1)&1] from overwrite while still being read. The co-resident
        // block computes through this stall.
        __syncthreads();
        if (cc + 1 < C_PER_BLOCK)
            stage_channel(slice0 + (size_t)(cc + 1) * NS * NK,
                          &sbuf[(cc + 1) & 1][0], t);  // in flight during compute

        const float4* lb = &sbuf[cc & 1][0];
        const float* prp = pr + ((size_t)(b * NC + ch0 + cc)) * 3;
        const float prx = prp[0], pry = prp[1], prz = prp[2];

#pragma unroll
        for (int j = 0; j < PX_PER_THREAD; ++j) {
            const float dx = gx[j]  - prx;
            const float dy = gy[j]  - pry;
            const float dz = gzv[j] - prz;
            const float drx = __builtin_amdgcn_sqrtf(fmaf(dx, dx, fmaf(dy, dy, dz * dz)));
            float s = fmaf(scale, drx, sbase[j]);         // fractional sample index
            s = fminf(fmaxf(s, 0.0f), (float)(NS - 1));   // clamp
            const float fi = fminf(floorf(s), (float)(NS - 2));
            const float w  = s - fi;
            const float wm = 1.0f - w;
            const int i0 = (int)fi;
            const float4 y0 = lb[i0];                     // adjacent 32 B:
            const float4 y1 = lb[i0 + 1];                 // 2x ds_read_b128
            acc[j].x = fmaf(y0.x, wm, fmaf(y1.x, w, acc[j].x));
            acc[j].y = fmaf(y0.y, wm, fmaf(y1.y, w, acc[j].y));
            acc[j].z = fmaf(y0.z, wm, fmaf(y1.z, w, acc[j].z));
            acc[j].w = fmaf(y0.w, wm, fmaf(y1.w, w, acc[j].w));
        }
    }

    if (ATOMIC) {
        float* ob = dst + (size_t)b * NM * NK;
#pragma unroll
        for (int j = 0; j < PX_PER_THREAD; ++j) {
            const int m = px0 + j * THREADS + t;
            float* op = ob + (size_t)m * NK;
            atomicAdd(op + 0, acc[j].x);
            atomicAdd(op + 1, acc[j].y);
            atomicAdd(op + 2, acc[j].z);
            atomicAdd(op + 3, acc[j].w);
        }
    } else {
        // partial[chunk][b][m] as float4 — disjoint per block, plain stores
        float4* pw = (float4*)dst + (size_t)(chunk * NBATCH + b) * NM;
#pragma unroll
        for (int j = 0; j < PX_PER_THREAD; ++j) {
            const int m = px0 + j * THREADS + t;
            pw[m] = acc[j];
        }
    }
}

// out[i] = sum over 8 chunk partials; i indexes float4 over [B*NM)
__global__ __launch_bounds__(256) void reduce_kernel(
    const float4* __restrict__ part, float4* __restrict__ out)
{
    const int i = blockIdx.x * 256 + threadIdx.x;
    const size_t stride = (size_t)NBATCH * NM;
    float4 a = part[i];
#pragma unroll
    for (int c = 1; c < N_CHUNKS; ++c) {
        const float4 v = part[c * stride + i];
        a.x += v.x; a.y += v.y; a.z += v.z; a.w += v.w;
    }
    out[i] = a;
}

extern "C" void kernel_launch(void* const* d_in, const int* in_sizes, int n_in,
                              void* d_out, int out_size, void* d_ws, size_t ws_size,
                              hipStream_t stream) {
    (void)in_sizes; (void)n_in;
    const float* rf = (const float*)d_in[0];
    const float* g  = (const float*)d_in[1];
    const float* pr = (const float*)d_in[2];
    const float* p  = (const float*)d_in[3];
    float* out = (float*)d_out;

    if (ws_size >= PART_BYTES) {
        das_kernel<false><<<NBLOCKS, THREADS, 0, stream>>>(rf, g, pr, p, (float*)d_ws);
        reduce_kernel<<<(NBATCH * NM) / 256, 256, 0, stream>>>((const float4*)d_ws,
                                                               (float4*)out);
    } else {
        hipMemsetAsync(d_out, 0, (size_t)out_size * sizeof(float), stream);
        das_kernel<true><<<NBLOCKS, THREADS, 0, stream>>>(rf, g, pr, p, out);
    }
}